// Round 19
// baseline (437.558 us; speedup 1.0000x reference)
//
#include <hip/hip_runtime.h>

typedef _Float16 f16x8 __attribute__((ext_vector_type(8)));
typedef unsigned short u16x4 __attribute__((ext_vector_type(4)));
typedef float f32x4 __attribute__((ext_vector_type(4)));

#define VMWAIT(N) asm volatile("s_waitcnt vmcnt(" #N ")" ::: "memory")
#define LGKM0()   asm volatile("s_waitcnt lgkmcnt(0)" ::: "memory")
#define FENCE()   asm volatile("" ::: "memory")
#define RBAR()    do { FENCE(); __builtin_amdgcn_s_barrier(); FENCE(); } while (0)

__device__ __forceinline__ u16x4 cvt4(float4 v) {
    u16x4 h;
    h[0] = __builtin_bit_cast(unsigned short, (_Float16)v.x);
    h[1] = __builtin_bit_cast(unsigned short, (_Float16)v.y);
    h[2] = __builtin_bit_cast(unsigned short, (_Float16)v.z);
    h[3] = __builtin_bit_cast(unsigned short, (_Float16)v.w);
    return h;
}

// ---------------------------------------------------------------------------
// Kernel 0: W [K,U] f32 -> fp16 image, layout [ktile=k>>5][u][k&31] u16.
// ---------------------------------------------------------------------------
__global__ void convert_w_kernel(const float* __restrict__ w1,
                                 const float* __restrict__ w2,
                                 unsigned short* __restrict__ w1img,
                                 unsigned short* __restrict__ w2img) {
    int u = blockIdx.x;
    int k = threadIdx.x + blockIdx.y * 256;
    size_t idx = (size_t)(k >> 5) * 16384 + (size_t)u * 32 + (k & 31);
    _Float16 h1 = (_Float16)w1[(size_t)k * 512 + u];
    _Float16 h2 = (_Float16)w2[(size_t)k * 512 + u];
    w1img[idx] = __builtin_bit_cast(unsigned short, h1);
    w2img[idx] = __builtin_bit_cast(unsigned short, h2);
}

// ---------------------------------------------------------------------------
// h2 kernel (round-5 structure, grid (32,2)) — proven, small cost
// ---------------------------------------------------------------------------
__device__ __forceinline__ void stage_a64(const float* __restrict__ src,
                                          char* As, int tid) {
    const int row = tid >> 2, q = tid & 3;
    const float* p = src + (size_t)row * 512 + q * 4;
    const int sw2 = ((row >> 1) & 3) << 4;
    char* wb = As + row * 64;
    float4 va[4], vb[4];
#define AISS(V, G) { _Pragma("unroll") \
    for (int j_ = 0; j_ < 4; ++j_) V[j_] = *(const float4*)(p + ((G) * 4 + j_) * 16); }
#define APRC(V, G) { _Pragma("unroll") \
    for (int j_ = 0; j_ < 4; ++j_) { \
        const int i_ = (G) * 4 + j_; \
        *(u16x4*)(wb + (i_ >> 1) * 4096 + ((q * 8 + (i_ & 1) * 32) ^ sw2)) = cvt4(V[j_]); } }
    AISS(va, 0); AISS(vb, 1);
    VMWAIT(4); APRC(va, 0); AISS(va, 2);
    VMWAIT(4); APRC(vb, 1); AISS(vb, 3);
    VMWAIT(4); APRC(va, 2); AISS(va, 4);
    VMWAIT(4); APRC(vb, 3); AISS(vb, 5);
    VMWAIT(4); APRC(va, 4); AISS(va, 6);
    VMWAIT(4); APRC(vb, 5); AISS(vb, 7);
    VMWAIT(4); APRC(va, 6);
    VMWAIT(0); APRC(vb, 7);
#undef AISS
#undef APRC
}

__device__ __forceinline__ void chunk_gemm(const char* __restrict__ bcol,
                                           const char* As, const int* aoff,
                                           f32x4 acc[4][4]) {
    f16x8 brA[4], brB[4], afA[4], afB[4];
    #pragma unroll
    for (int i = 0; i < 4; ++i)
        #pragma unroll
        for (int j = 0; j < 4; ++j) acc[i][j] = (f32x4){0.f, 0.f, 0.f, 0.f};
    #pragma unroll
    for (int j = 0; j < 4; ++j) brA[j] = *(const f16x8*)(bcol + j * 1024);
    #pragma unroll
    for (int j = 0; j < 4; ++j) brB[j] = *(const f16x8*)(bcol + 32768 + j * 1024);
    #pragma unroll
    for (int i = 0; i < 4; ++i) afA[i] = *(const f16x8*)(As + aoff[i]);
    #pragma unroll
    for (int tt = 0; tt < 8; ++tt) {
        const int t0 = 2 * tt, t1 = t0 + 1;
        #pragma unroll
        for (int i = 0; i < 4; ++i)
            afB[i] = *(const f16x8*)(As + t1 * 4096 + aoff[i]);
        VMWAIT(4);
        #pragma unroll
        for (int i = 0; i < 4; ++i)
            #pragma unroll
            for (int j = 0; j < 4; ++j)
                acc[i][j] = __builtin_amdgcn_mfma_f32_16x16x32_f16(afA[i], brA[j], acc[i][j], 0, 0, 0);
        if (t0 < 14) {
            #pragma unroll
            for (int j = 0; j < 4; ++j)
                brA[j] = *(const f16x8*)(bcol + (t0 + 2) * 32768 + j * 1024);
        }
        if (t1 < 15) {
            #pragma unroll
            for (int i = 0; i < 4; ++i)
                afA[i] = *(const f16x8*)(As + (t1 + 1) * 4096 + aoff[i]);
        }
        if (t1 < 14) { VMWAIT(4); } else { VMWAIT(0); }
        #pragma unroll
        for (int i = 0; i < 4; ++i)
            #pragma unroll
            for (int j = 0; j < 4; ++j)
                acc[i][j] = __builtin_amdgcn_mfma_f32_16x16x32_f16(afB[i], brB[j], acc[i][j], 0, 0, 0);
        if (t1 < 14) {
            #pragma unroll
            for (int j = 0; j < 4; ++j)
                brB[j] = *(const f16x8*)(bcol + (t1 + 2) * 32768 + j * 1024);
        }
    }
}

__global__ __launch_bounds__(256, 2)
void h2_gemm_kernel(const float* __restrict__ hidden,
                    const char* __restrict__ w2img,
                    const float* __restrict__ b2,
                    float* __restrict__ h2o) {
    __shared__ char As[65536];
    const int tid = threadIdx.x, bm = blockIdx.x, bn = blockIdx.y;
    const int lane = tid & 63, wid = tid >> 6;
    const int lane16 = lane & 15, g = lane >> 4;
    stage_a64(hidden + (size_t)bm * 32768, As, tid);
    __syncthreads();
    int aoff[4];
    #pragma unroll
    for (int i = 0; i < 4; ++i)
        aoff[i] = (i * 16 + lane16) * 64 + ((g ^ ((lane16 >> 1) & 3)) << 4);
    const char* bcol = w2img + (size_t)(bn * 256 + wid * 64 + lane16) * 64 + g * 16;
    f32x4 acc[4][4];
    chunk_gemm(bcol, As, aoff, acc);
    #pragma unroll
    for (int j = 0; j < 4; ++j) {
        int col = bn * 256 + wid * 64 + j * 16 + lane16;
        float bb = b2[col];
        #pragma unroll
        for (int i = 0; i < 4; ++i)
            #pragma unroll
            for (int r = 0; r < 4; ++r)
                h2o[(size_t)(bm * 64 + i * 16 + g * 4 + r) * 512 + col] = acc[i][j][r] + bb;
    }
}

// ---------------------------------------------------------------------------
// r13's proven hot loop + VMWAIT(0) at entry (cleans per-wave FIFO of the
// previous iteration's out-store before the counted B ledger starts).
// ---------------------------------------------------------------------------
__device__ __forceinline__ void chunk64_lowreg(const char* __restrict__ bcol,
                                               const char* As, const int* aoff,
                                               f32x4 acc[4][4]) {
    f16x8 brE[4], brO[4];
    #pragma unroll
    for (int i = 0; i < 4; ++i)
        #pragma unroll
        for (int j = 0; j < 4; ++j) acc[i][j] = (f32x4){0.f, 0.f, 0.f, 0.f};
    VMWAIT(0);
    FENCE();
    #pragma unroll
    for (int j = 0; j < 4; ++j) brE[j] = *(const f16x8*)(bcol + j * 1024);
    #pragma unroll
    for (int j = 0; j < 4; ++j) brO[j] = *(const f16x8*)(bcol + 32768 + j * 1024);
    #pragma unroll
    for (int t = 0; t < 16; ++t) {
        f16x8 af[4];
        #pragma unroll
        for (int i = 0; i < 4; ++i)
            af[i] = *(const f16x8*)(As + t * 4096 + aoff[i]);
        if (t < 14) { VMWAIT(4); } else { VMWAIT(0); }
        LGKM0();
        if ((t & 1) == 0) {
            #pragma unroll
            for (int i = 0; i < 4; ++i)
                #pragma unroll
                for (int j = 0; j < 4; ++j)
                    acc[i][j] = __builtin_amdgcn_mfma_f32_16x16x32_f16(af[i], brE[j], acc[i][j], 0, 0, 0);
            FENCE();
            if (t < 14) {
                #pragma unroll
                for (int j = 0; j < 4; ++j)
                    brE[j] = *(const f16x8*)(bcol + (t + 2) * 32768 + j * 1024);
            }
        } else {
            #pragma unroll
            for (int i = 0; i < 4; ++i)
                #pragma unroll
                for (int j = 0; j < 4; ++j)
                    acc[i][j] = __builtin_amdgcn_mfma_f32_16x16x32_f16(af[i], brO[j], acc[i][j], 0, 0, 0);
            FENCE();
            if (t < 14) {
                #pragma unroll
                for (int j = 0; j < 4; ++j)
                    brO[j] = *(const f16x8*)(bcol + (t + 2) * 32768 + j * 1024);
            }
        }
        FENCE();
    }
}

// ---------------------------------------------------------------------------
// Fused kernel: PRODUCER/CONSUMER waves, per-wave vmcnt FIFOs.
// 256 blocks x 8 batches, 1024 thr = 8 consumer waves (tid<512; r13 k-loop,
// 64 cols each) + 8 producer waves (tid>=512; stage batch n+1 to As[n^1]).
// 1 block/CU (LDS 138KB), 4 waves/SIMD. Raw s_barrier x3 per batch; producer
// loads are REGISTER loads issued pre-#1, drained (own-wave VMWAIT(0)) and
// written to the idle LDS buffer between #2 and #3 (under consumer context).
// ---------------------------------------------------------------------------
__global__ __launch_bounds__(1024, 4)
void fused_all_kernel(const float* __restrict__ feat,
                      const char* __restrict__ w1img,
                      const float* __restrict__ h2,
                      const float* __restrict__ b1,
                      const float* __restrict__ wv,
                      float* __restrict__ out) {
    __shared__ char As[2][65536];
    __shared__ float hhs[2][512];
    __shared__ float wvs[512];
    __shared__ float spl[512];
    __shared__ float wsm[64];
    __shared__ float cpart[512];

    const int tid = threadIdx.x;
    const bool consumer = (tid < 512);
    const int blk = (blockIdx.x & 7) * 32 + (blockIdx.x >> 3);   // XCD swizzle
    const int b0 = blk * 8;
    const int lane16 = tid & 15, g = (tid >> 4) & 3;
    const int wid = tid >> 6;                  // consumer: 0..7

    // producer coords (r13's 512-thread stage mapping)
    const int pid = tid & 511;
    const int prow = pid >> 3, pq = pid & 7;
    const int pswz = (((pq >> 1) ^ ((prow >> 1) & 3)) << 4) + (pq & 1) * 8;

    // ---- prologue: consts + ALL 1024 threads stage batch b0 -> As[0] ----
    float b1v = b1[pid];
    float wvv0 = 0.f, h2v0 = 0.f;
    if (consumer) {
        h2v0 = h2[(size_t)b0 * 512 + tid];
        wvv0 = wv[tid];
    }
    FENCE();
    {
        const int r0 = tid >> 4, sub = tid & 15, q8 = sub >> 1, koff = (sub & 1) * 8;
        const float* p0 = feat + (size_t)b0 * 32768 + (size_t)r0 * 512 + q8 * 4;
        char* wb0 = As[0] + r0 * 64 + (((q8 >> 1) ^ ((r0 >> 1) & 3)) << 4) + (q8 & 1) * 8;
        float4 v[8];
        #pragma unroll
        for (int j = 0; j < 8; ++j) v[j] = *(const float4*)(p0 + (koff + j) * 32);
        FENCE();
        VMWAIT(4);
        if (consumer) { wvs[tid] = wvv0; hhs[0][tid] = b1v + h2v0; }
        #pragma unroll
        for (int j = 0; j < 4; ++j)
            *(u16x4*)(wb0 + (koff + j) * 4096) = cvt4(v[j]);
        VMWAIT(0);
        #pragma unroll
        for (int j = 4; j < 8; ++j)
            *(u16x4*)(wb0 + (koff + j) * 4096) = cvt4(v[j]);
    }
    LGKM0();
    RBAR();

    int aoff[4];
    #pragma unroll
    for (int i = 0; i < 4; ++i)
        aoff[i] = (i * 16 + lane16) * 64 + ((g ^ ((lane16 >> 1) & 3)) << 4);
    const char* bcol = w1img + (size_t)(wid * 64 + lane16) * 64 + g * 16;

    // ---- batch loop ----
    #pragma unroll 1
    for (int it = 0; it < 8; ++it) {
        const int cur = it & 1;
        float4 pv[16];
        float h2n = 0.f;
        float ax = 0.f, ay = 0.f;

        if (consumer) {
            f32x4 acc[4][4];
            chunk64_lowreg(bcol, As[cur], aoff, acc);
            float hhv[4], wvv[4];
            #pragma unroll
            for (int j = 0; j < 4; ++j) {
                int col = wid * 64 + j * 16 + lane16;
                hhv[j] = hhs[cur][col];
                wvv[j] = wvs[col];
            }
            #pragma unroll
            for (int i = 0; i < 4; ++i)
                #pragma unroll
                for (int r = 0; r < 4; ++r) {
                    float s = 0.f;
                    #pragma unroll
                    for (int j = 0; j < 4; ++j) {
                        float h = acc[i][j][r] + hhv[j];
                        float ex = __expf(2.f * h);
                        s += (1.f - 2.f * __builtin_amdgcn_rcpf(ex + 1.f)) * wvv[j];
                    }
                    s += __shfl_xor(s, 1); s += __shfl_xor(s, 2);
                    s += __shfl_xor(s, 4); s += __shfl_xor(s, 8);
                    if (lane16 == 0) spl[(i * 16 + g * 4 + r) * 8 + wid] = s;
                }
            LGKM0();
        } else if (it < 7) {
            // producers: issue batch it+1's loads (fly across barriers)
            const float* pn = feat + (size_t)(b0 + it + 1) * 32768 +
                              (size_t)prow * 512 + pq * 4;
            #pragma unroll
            for (int j = 0; j < 16; ++j) pv[j] = *(const float4*)(pn + j * 32);
            h2n = h2[(size_t)(b0 + it + 1) * 512 + pid];
            FENCE();
        }
        RBAR();   // #1: spl ready

        if (tid < 64) {
            float s = ((spl[tid * 8 + 0] + spl[tid * 8 + 1]) + (spl[tid * 8 + 2] + spl[tid * 8 + 3])) +
                      ((spl[tid * 8 + 4] + spl[tid * 8 + 5]) + (spl[tid * 8 + 6] + spl[tid * 8 + 7]));
            float m = s;
            #pragma unroll
            for (int off = 32; off; off >>= 1) m = fmaxf(m, __shfl_xor(m, off));
            float e = __expf(s - m);
            float sum = e;
            #pragma unroll
            for (int off = 32; off; off >>= 1) sum += __shfl_xor(sum, off);
            wsm[tid] = e / sum;
            LGKM0();
        }
        RBAR();   // #2: wsm ready

        if (consumer) {
            // context from LDS fp16 A (r13 s-rotated)
            const int t2 = tid & 255, half = tid >> 8;
            const int kst = t2 >> 4;
            const int base = kst * 4096 + (t2 & 3) * 4;
            const int ksl = (t2 >> 2) & 3;
            #pragma unroll 8
            for (int si = 0; si < 32; ++si) {
                const int s = half * 32 + ((si + kst) & 31);
                unsigned vv = *(const unsigned*)(As[cur] + base + s * 64 +
                                                 ((ksl ^ ((s >> 1) & 3)) << 4));
                float w = wsm[s];
                ax += w * (float)__builtin_bit_cast(_Float16, (unsigned short)(vv & 0xffffu));
                ay += w * (float)__builtin_bit_cast(_Float16, (unsigned short)(vv >> 16));
            }
            if (half == 1) { cpart[t2 * 2] = ax; cpart[t2 * 2 + 1] = ay; }
            LGKM0();
        } else if (it < 7) {
            // producers: drain OWN loads, write As[cur^1] + hhs[next]
            VMWAIT(0);
            FENCE();
            char* pwb = As[cur ^ 1] + prow * 64 + pswz;
            #pragma unroll
            for (int j = 0; j < 16; ++j)
                *(u16x4*)(pwb + j * 4096) = cvt4(pv[j]);
            hhs[cur ^ 1][pid] = b1v + h2n;
            LGKM0();
        }
        RBAR();   // #3: cpart ready AND As[next]/hhs[next] staged

        if (consumer && (tid >> 8) == 0) {
            const int t2 = tid & 255;
            ax += cpart[t2 * 2]; ay += cpart[t2 * 2 + 1];
            ((float2*)out)[(size_t)(b0 + it) * 256 + t2] = make_float2(ax, ay);
        }
    }
}

// ---------------------------------------------------------------------------
extern "C" void kernel_launch(void* const* d_in, const int* in_sizes, int n_in,
                              void* d_out, int out_size, void* d_ws, size_t ws_size,
                              hipStream_t stream) {
    (void)in_sizes; (void)n_in; (void)out_size; (void)ws_size;
    const float* feat   = (const float*)d_in[0];   // [2048,64,512]
    const float* hidden = (const float*)d_in[1];   // [2048,512]
    const float* W1     = (const float*)d_in[2];   // [512,512]
    const float* b1     = (const float*)d_in[3];   // [512]
    const float* W2     = (const float*)d_in[4];   // [512,512]
    const float* b2     = (const float*)d_in[5];   // [512]
    const float* Wv     = (const float*)d_in[6];   // [512,1]
    // d_in[7] = bv: softmax shift-invariant, unused.
    float* out = (float*)d_out;                    // [2048,512]

    char* ws = (char*)d_ws;
    unsigned short* w1img = (unsigned short*)(ws);            // 512 KB
    unsigned short* w2img = (unsigned short*)(ws + 524288);   // 512 KB
    float* h2 = (float*)(ws + 1048576);                       // 4 MB

    convert_w_kernel<<<dim3(512, 2), dim3(256), 0, stream>>>(W1, W2, w1img, w2img);
    h2_gemm_kernel<<<dim3(32, 2), dim3(256), 0, stream>>>(hidden, (const char*)w2img, b2, h2);
    fused_all_kernel<<<dim3(256), dim3(1024), 0, stream>>>(feat, (const char*)w1img, h2, b1, Wv, out);
}

// Round 20
// 139.437 us; speedup vs baseline: 3.1380x; 3.1380x over previous
//
#include <hip/hip_runtime.h>

typedef _Float16 f16x8 __attribute__((ext_vector_type(8)));
typedef unsigned short u16x4 __attribute__((ext_vector_type(4)));
typedef float f32x4 __attribute__((ext_vector_type(4)));

#define VMWAIT(N) asm volatile("s_waitcnt vmcnt(" #N ")" ::: "memory")
#define LGKM0()   asm volatile("s_waitcnt lgkmcnt(0)" ::: "memory")
#define FENCE()   asm volatile("" ::: "memory")
#define RBAR()    do { FENCE(); __builtin_amdgcn_s_barrier(); FENCE(); } while (0)

__device__ __forceinline__ u16x4 cvt4(float4 v) {
    u16x4 h;
    h[0] = __builtin_bit_cast(unsigned short, (_Float16)v.x);
    h[1] = __builtin_bit_cast(unsigned short, (_Float16)v.y);
    h[2] = __builtin_bit_cast(unsigned short, (_Float16)v.z);
    h[3] = __builtin_bit_cast(unsigned short, (_Float16)v.w);
    return h;
}

// ---------------------------------------------------------------------------
// Kernel 0: W [K,U] f32 -> fp16 image, layout [ktile=k>>5][u][k&31] u16.
// ---------------------------------------------------------------------------
__global__ void convert_w_kernel(const float* __restrict__ w1,
                                 const float* __restrict__ w2,
                                 unsigned short* __restrict__ w1img,
                                 unsigned short* __restrict__ w2img) {
    int u = blockIdx.x;
    int k = threadIdx.x + blockIdx.y * 256;
    size_t idx = (size_t)(k >> 5) * 16384 + (size_t)u * 32 + (k & 31);
    _Float16 h1 = (_Float16)w1[(size_t)k * 512 + u];
    _Float16 h2 = (_Float16)w2[(size_t)k * 512 + u];
    w1img[idx] = __builtin_bit_cast(unsigned short, h1);
    w2img[idx] = __builtin_bit_cast(unsigned short, h2);
}

// ---------------------------------------------------------------------------
// h2 kernel (round-5 structure, grid (32,2)) — proven, small cost
// ---------------------------------------------------------------------------
__device__ __forceinline__ void stage_a64(const float* __restrict__ src,
                                          char* As, int tid) {
    const int row = tid >> 2, q = tid & 3;
    const float* p = src + (size_t)row * 512 + q * 4;
    const int sw2 = ((row >> 1) & 3) << 4;
    char* wb = As + row * 64;
    float4 va[4], vb[4];
#define AISS(V, G) { _Pragma("unroll") \
    for (int j_ = 0; j_ < 4; ++j_) V[j_] = *(const float4*)(p + ((G) * 4 + j_) * 16); }
#define APRC(V, G) { _Pragma("unroll") \
    for (int j_ = 0; j_ < 4; ++j_) { \
        const int i_ = (G) * 4 + j_; \
        *(u16x4*)(wb + (i_ >> 1) * 4096 + ((q * 8 + (i_ & 1) * 32) ^ sw2)) = cvt4(V[j_]); } }
    AISS(va, 0); AISS(vb, 1);
    VMWAIT(4); APRC(va, 0); AISS(va, 2);
    VMWAIT(4); APRC(vb, 1); AISS(vb, 3);
    VMWAIT(4); APRC(va, 2); AISS(va, 4);
    VMWAIT(4); APRC(vb, 3); AISS(vb, 5);
    VMWAIT(4); APRC(va, 4); AISS(va, 6);
    VMWAIT(4); APRC(vb, 5); AISS(vb, 7);
    VMWAIT(4); APRC(va, 6);
    VMWAIT(0); APRC(vb, 7);
#undef AISS
#undef APRC
}

__device__ __forceinline__ void chunk_gemm(const char* __restrict__ bcol,
                                           const char* As, const int* aoff,
                                           f32x4 acc[4][4]) {
    f16x8 brA[4], brB[4], afA[4], afB[4];
    #pragma unroll
    for (int i = 0; i < 4; ++i)
        #pragma unroll
        for (int j = 0; j < 4; ++j) acc[i][j] = (f32x4){0.f, 0.f, 0.f, 0.f};
    #pragma unroll
    for (int j = 0; j < 4; ++j) brA[j] = *(const f16x8*)(bcol + j * 1024);
    #pragma unroll
    for (int j = 0; j < 4; ++j) brB[j] = *(const f16x8*)(bcol + 32768 + j * 1024);
    #pragma unroll
    for (int i = 0; i < 4; ++i) afA[i] = *(const f16x8*)(As + aoff[i]);
    #pragma unroll
    for (int tt = 0; tt < 8; ++tt) {
        const int t0 = 2 * tt, t1 = t0 + 1;
        #pragma unroll
        for (int i = 0; i < 4; ++i)
            afB[i] = *(const f16x8*)(As + t1 * 4096 + aoff[i]);
        VMWAIT(4);
        #pragma unroll
        for (int i = 0; i < 4; ++i)
            #pragma unroll
            for (int j = 0; j < 4; ++j)
                acc[i][j] = __builtin_amdgcn_mfma_f32_16x16x32_f16(afA[i], brA[j], acc[i][j], 0, 0, 0);
        if (t0 < 14) {
            #pragma unroll
            for (int j = 0; j < 4; ++j)
                brA[j] = *(const f16x8*)(bcol + (t0 + 2) * 32768 + j * 1024);
        }
        if (t1 < 15) {
            #pragma unroll
            for (int i = 0; i < 4; ++i)
                afA[i] = *(const f16x8*)(As + (t1 + 1) * 4096 + aoff[i]);
        }
        if (t1 < 14) { VMWAIT(4); } else { VMWAIT(0); }
        #pragma unroll
        for (int i = 0; i < 4; ++i)
            #pragma unroll
            for (int j = 0; j < 4; ++j)
                acc[i][j] = __builtin_amdgcn_mfma_f32_16x16x32_f16(afB[i], brB[j], acc[i][j], 0, 0, 0);
        if (t1 < 14) {
            #pragma unroll
            for (int j = 0; j < 4; ++j)
                brB[j] = *(const f16x8*)(bcol + (t1 + 2) * 32768 + j * 1024);
        }
    }
}

__global__ __launch_bounds__(256, 2)
void h2_gemm_kernel(const float* __restrict__ hidden,
                    const char* __restrict__ w2img,
                    const float* __restrict__ b2,
                    float* __restrict__ h2o) {
    __shared__ char As[65536];
    const int tid = threadIdx.x, bm = blockIdx.x, bn = blockIdx.y;
    const int lane = tid & 63, wid = tid >> 6;
    const int lane16 = lane & 15, g = lane >> 4;
    stage_a64(hidden + (size_t)bm * 32768, As, tid);
    __syncthreads();
    int aoff[4];
    #pragma unroll
    for (int i = 0; i < 4; ++i)
        aoff[i] = (i * 16 + lane16) * 64 + ((g ^ ((lane16 >> 1) & 3)) << 4);
    const char* bcol = w2img + (size_t)(bn * 256 + wid * 64 + lane16) * 64 + g * 16;
    f32x4 acc[4][4];
    chunk_gemm(bcol, As, aoff, acc);
    #pragma unroll
    for (int j = 0; j < 4; ++j) {
        int col = bn * 256 + wid * 64 + j * 16 + lane16;
        float bb = b2[col];
        #pragma unroll
        for (int i = 0; i < 4; ++i)
            #pragma unroll
            for (int r = 0; r < 4; ++r)
                h2o[(size_t)(bm * 64 + i * 16 + g * 4 + r) * 512 + col] = acc[i][j][r] + bb;
    }
}

// ---------------------------------------------------------------------------
// Single-set-A chunk GEMM — r13's exact hot loop (coarse LGKM0 KEPT: r17
// proved removing it regresses; the drain acts as a beneficial sched fence).
// ---------------------------------------------------------------------------
__device__ __forceinline__ void chunk64_lowreg(const char* __restrict__ bcol,
                                               const char* As, const int* aoff,
                                               f32x4 acc[4][4]) {
    f16x8 brE[4], brO[4];
    #pragma unroll
    for (int i = 0; i < 4; ++i)
        #pragma unroll
        for (int j = 0; j < 4; ++j) acc[i][j] = (f32x4){0.f, 0.f, 0.f, 0.f};
    #pragma unroll
    for (int j = 0; j < 4; ++j) brE[j] = *(const f16x8*)(bcol + j * 1024);
    #pragma unroll
    for (int j = 0; j < 4; ++j) brO[j] = *(const f16x8*)(bcol + 32768 + j * 1024);
    #pragma unroll
    for (int t = 0; t < 16; ++t) {
        f16x8 af[4];
        #pragma unroll
        for (int i = 0; i < 4; ++i)
            af[i] = *(const f16x8*)(As + t * 4096 + aoff[i]);
        if (t < 14) { VMWAIT(4); } else { VMWAIT(0); }
        LGKM0();
        if ((t & 1) == 0) {
            #pragma unroll
            for (int i = 0; i < 4; ++i)
                #pragma unroll
                for (int j = 0; j < 4; ++j)
                    acc[i][j] = __builtin_amdgcn_mfma_f32_16x16x32_f16(af[i], brE[j], acc[i][j], 0, 0, 0);
            FENCE();
            if (t < 14) {
                #pragma unroll
                for (int j = 0; j < 4; ++j)
                    brE[j] = *(const f16x8*)(bcol + (t + 2) * 32768 + j * 1024);
            }
        } else {
            #pragma unroll
            for (int i = 0; i < 4; ++i)
                #pragma unroll
                for (int j = 0; j < 4; ++j)
                    acc[i][j] = __builtin_amdgcn_mfma_f32_16x16x32_f16(af[i], brO[j], acc[i][j], 0, 0, 0);
            FENCE();
            if (t < 14) {
                #pragma unroll
                for (int j = 0; j < 4; ++j)
                    brO[j] = *(const f16x8*)(bcol + (t + 2) * 32768 + j * 1024);
            }
        }
        FENCE();
    }
}

// ---------------------------------------------------------------------------
// Fused kernel (r13 structure + bijective XCD block swizzle — the r18 best):
// all-16-upfront stage with grouped drains, consts prestaged to LDS,
// s-rotated context. 2048 blocks x 512 thr, 2 blocks/CU -> 4 waves/SIMD.
// ---------------------------------------------------------------------------
__global__ __launch_bounds__(512, 4)
void fused_all_kernel(const float* __restrict__ feat,
                      const char* __restrict__ w1img,
                      const float* __restrict__ h2,
                      const float* __restrict__ b1,
                      const float* __restrict__ wv,
                      float* __restrict__ out) {
    __shared__ char As[65536];
    __shared__ float hhs[512];
    __shared__ float wvs[512];
    __shared__ float spl[512];
    __shared__ float wsm[64];
    __shared__ float cpart[512];

    const int tid = threadIdx.x;
    const int bm = (blockIdx.x & 7) * 256 + (blockIdx.x >> 3);   // XCD swizzle
    const int lane16 = tid & 15, g = (tid >> 4) & 3;
    const int wid = tid >> 6;

    // ---- stage: consts + all 16 feat loads issued up front; grouped drains
    {
        const int row = tid >> 3, q = tid & 7;
        const float* p = feat + (size_t)bm * 32768 + (size_t)row * 512 + q * 4;
        char* wb = As + row * 64 + (((q >> 1) ^ ((row >> 1) & 3)) << 4) + (q & 1) * 8;
        // FIFO: [b1, h2, wv, v0..v15]  (19 outstanding)
        float hb = b1[tid];
        float hv = h2[(size_t)bm * 512 + tid];
        float wv_ = wv[tid];
        FENCE();
        float4 v[16];
        #pragma unroll
        for (int j = 0; j < 16; ++j) v[j] = *(const float4*)(p + j * 32);
        FENCE();
        VMWAIT(16);                 // consts landed
        hhs[tid] = hb + hv;
        wvs[tid] = wv_;
        VMWAIT(12);
        #pragma unroll
        for (int j = 0; j < 4; ++j)  *(u16x4*)(wb + j * 4096) = cvt4(v[j]);
        VMWAIT(8);
        #pragma unroll
        for (int j = 4; j < 8; ++j)  *(u16x4*)(wb + j * 4096) = cvt4(v[j]);
        VMWAIT(4);
        #pragma unroll
        for (int j = 8; j < 12; ++j) *(u16x4*)(wb + j * 4096) = cvt4(v[j]);
        VMWAIT(0);
        #pragma unroll
        for (int j = 12; j < 16; ++j) *(u16x4*)(wb + j * 4096) = cvt4(v[j]);
    }
    LGKM0();
    RBAR();

    // ---- GEMM: wave owns 64 cols ----
    int aoff[4];
    #pragma unroll
    for (int i = 0; i < 4; ++i)
        aoff[i] = (i * 16 + lane16) * 64 + ((g ^ ((lane16 >> 1) & 3)) << 4);
    const char* bcol = w1img + (size_t)(wid * 64 + lane16) * 64 + g * 16;
    f32x4 acc[4][4];
    chunk64_lowreg(bcol, As, aoff, acc);

    // epilogue constants from LDS (prestaged; no global latency here)
    float hhv[4], wvv[4];
    #pragma unroll
    for (int j = 0; j < 4; ++j) {
        int col = wid * 64 + j * 16 + lane16;
        hhv[j] = hhs[col];
        wvv[j] = wvs[col];
    }

    // ---- scores: tanh + dot(Wv) ----
    #pragma unroll
    for (int i = 0; i < 4; ++i)
        #pragma unroll
        for (int r = 0; r < 4; ++r) {
            float s = 0.f;
            #pragma unroll
            for (int j = 0; j < 4; ++j) {
                float h = acc[i][j][r] + hhv[j];
                float ex = __expf(2.f * h);
                s += (1.f - 2.f * __builtin_amdgcn_rcpf(ex + 1.f)) * wvv[j];
            }
            s += __shfl_xor(s, 1); s += __shfl_xor(s, 2);
            s += __shfl_xor(s, 4); s += __shfl_xor(s, 8);
            if (lane16 == 0) spl[(i * 16 + g * 4 + r) * 8 + wid] = s;
        }
    LGKM0();
    RBAR();

    // ---- softmax over S=64 (bv shift is a softmax no-op) ----
    if (tid < 64) {
        float s = ((spl[tid * 8 + 0] + spl[tid * 8 + 1]) + (spl[tid * 8 + 2] + spl[tid * 8 + 3])) +
                  ((spl[tid * 8 + 4] + spl[tid * 8 + 5]) + (spl[tid * 8 + 6] + spl[tid * 8 + 7]));
        float m = s;
        #pragma unroll
        for (int off = 32; off; off >>= 1) m = fmaxf(m, __shfl_xor(m, off));
        float e = __expf(s - m);
        float sum = e;
        #pragma unroll
        for (int off = 32; off; off >>= 1) sum += __shfl_xor(sum, off);
        wsm[tid] = e / sum;
        LGKM0();
    }
    RBAR();

    // ---- context from LDS fp16 A; per-ktile s-rotation spreads banks ----
    {
        const int t2 = tid & 255, half = tid >> 8;
        const int kst = t2 >> 4;                    // ktile of col pair
        const int base = kst * 4096 + (t2 & 3) * 4;
        const int ksl = (t2 >> 2) & 3;
        float ax = 0.f, ay = 0.f;
        #pragma unroll 8
        for (int si = 0; si < 32; ++si) {
            const int s = half * 32 + ((si + kst) & 31);
            unsigned vv = *(const unsigned*)(As + base + s * 64 +
                                             ((ksl ^ ((s >> 1) & 3)) << 4));
            float w = wsm[s];
            ax += w * (float)__builtin_bit_cast(_Float16, (unsigned short)(vv & 0xffffu));
            ay += w * (float)__builtin_bit_cast(_Float16, (unsigned short)(vv >> 16));
        }
        if (half == 1) { cpart[t2 * 2] = ax; cpart[t2 * 2 + 1] = ay; }
        LGKM0();
        RBAR();
        if (half == 0) {
            ax += cpart[t2 * 2]; ay += cpart[t2 * 2 + 1];
            ((float2*)out)[(size_t)bm * 256 + t2] = make_float2(ax, ay);
        }
    }
}

// ---------------------------------------------------------------------------
extern "C" void kernel_launch(void* const* d_in, const int* in_sizes, int n_in,
                              void* d_out, int out_size, void* d_ws, size_t ws_size,
                              hipStream_t stream) {
    (void)in_sizes; (void)n_in; (void)out_size; (void)ws_size;
    const float* feat   = (const float*)d_in[0];   // [2048,64,512]
    const float* hidden = (const float*)d_in[1];   // [2048,512]
    const float* W1     = (const float*)d_in[2];   // [512,512]
    const float* b1     = (const float*)d_in[3];   // [512]
    const float* W2     = (const float*)d_in[4];   // [512,512]
    const float* b2     = (const float*)d_in[5];   // [512]
    const float* Wv     = (const float*)d_in[6];   // [512,1]
    // d_in[7] = bv: softmax shift-invariant, unused.
    float* out = (float*)d_out;                    // [2048,512]

    char* ws = (char*)d_ws;
    unsigned short* w1img = (unsigned short*)(ws);            // 512 KB
    unsigned short* w2img = (unsigned short*)(ws + 524288);   // 512 KB
    float* h2 = (float*)(ws + 1048576);                       // 4 MB

    convert_w_kernel<<<dim3(512, 2), dim3(256), 0, stream>>>(W1, W2, w1img, w2img);
    h2_gemm_kernel<<<dim3(32, 2), dim3(256), 0, stream>>>(hidden, (const char*)w2img, b2, h2);
    fused_all_kernel<<<dim3(2048), dim3(512), 0, stream>>>(feat, (const char*)w1img, h2, b1, Wv, out);
}